// Round 5
// baseline (165.545 us; speedup 1.0000x reference)
//
#include <hip/hip_runtime.h>
#include <stdint.h>

// pairs_of_pairs: fused [concat -> conv1x1+relu x3]
// B=32, C=64, S=64, CC=128, OC=256. 2016 rows of 64 positions.
// R4: 2 rows/block (b0, b0+16), grid 1008, 512 thr. LDS = exactly 64KB so
// 2 blocks/CU fit (R3: 72KB -> 1 block/CU, serial execution). Rolled-x chunk
// is NOT stored: layer-0 reads chunk2 at shifted pos. X = 4 chunk regions
// [128pos][64ch] bf16 (16KB each); stg double-buffer lives in chunk3 region
// during build (chunk3 only written by layer-0 epilogue). launch_bounds
// (512,4): 4 waves/EU = 2 blocks/CU (2nd arg is waves per EU!).

typedef __attribute__((ext_vector_type(8))) __bf16 bf16x8;
typedef __attribute__((ext_vector_type(4))) float f32x4;
typedef __attribute__((ext_vector_type(4))) unsigned short u16x4;
typedef __attribute__((ext_vector_type(8))) unsigned short u16x8;

__device__ __forceinline__ unsigned short f2bf(float f) {
  unsigned int u = __builtin_bit_cast(unsigned int, f);
  u += 0x7FFFu + ((u >> 16) & 1u);
  return (unsigned short)(u >> 16);
}

// X: 4 chunk regions of [128 pos][64 ch] bf16 (8192 elems each).
// Within chunk: 16B-slot = pos*8 + ((c6/8) ^ (pos&7)) -> max 2-way (free)
// on both ds_read_b128 B-fragments and epilogue writes.
__device__ __forceinline__ int xaddr(int pos, int c) {
  int slot = (pos << 3) + ((((c & 63) >> 3) ^ pos) & 7);
  return ((c >> 6) << 13) + (slot << 3) + (c & 7);
}

__global__ void wconv_kernel(const float* __restrict__ W1, const float* __restrict__ W2,
                             const float* __restrict__ W3, unsigned short* __restrict__ wb) {
  int i = (blockIdx.x * 256 + threadIdx.x) * 4;  // grid 64 -> 65536 per layer
  const float* Ws[3] = {W1, W2, W3};
#pragma unroll
  for (int L = 0; L < 3; ++L) {
    f32x4 a = *(const f32x4*)(Ws[L] + i);
    u16x4 p;
#pragma unroll
    for (int v = 0; v < 4; ++v) p[v] = f2bf(a[v]);
    *(u16x4*)(wb + L * 65536 + i) = p;
  }
}

__global__ __launch_bounds__(512, 4)
void fused_kernel(const float* __restrict__ x, const float* __restrict__ xc,
                  const unsigned short* __restrict__ wb,
                  const float* __restrict__ b1, const float* __restrict__ b2,
                  const float* __restrict__ b3, float* __restrict__ out) {
  __shared__ __align__(16) unsigned char lraw[65536];
  unsigned short* X = (unsigned short*)lraw;                // 64KB, 4 chunks
  float* bounce = (float*)lraw;                             // 32KB epilogue reuse
  unsigned short* stg0 = (unsigned short*)(lraw + 49152);   // 8KB, in chunk3 region
  unsigned short* stg1 = (unsigned short*)(lraw + 57344);   // 8KB, in chunk3 region

  const int r = blockIdx.x;       // 0..1007
  const int b0 = r / 63;          // 0..15 ; row1 uses b0+16
  const int dd = r % 63;
  const int d = dd + 1;
  const int tid = threadIdx.x;    // 0..511
  const int lane = tid & 63;
  const int g16 = lane >> 4;
  const int l16 = lane & 15;
  const int wv = tid >> 6;        // wave 0..7

  // ---------------- build layer-0 input tiles (2 rows, 6 rounds) ----------
  // round rd: rr = rd/3 (row), ck = rd%3 (0: xc ch0-63, 1: xc ch64-127, 2: x).
  // stg double-buffered -> 1 barrier/round. No rolled chunk stored.
  auto ldrnd = [&](int rd, f32x4 ld[2]) {
    int rr = rd / 3;
    int ck = rd - rr * 3;
    int b = b0 + 16 * rr;
#pragma unroll
    for (int it = 0; it < 2; ++it) {
      int u = it * 512 + tid, cc = u >> 4, i4 = (u & 15) << 2;
      const float* src = (ck < 2)
          ? xc + (((b * 128 + ck * 64 + cc) * 63) + dd) * 64 + i4
          : x + (b * 64 + cc) * 64 + i4;
      ld[it] = *(const f32x4*)src;
    }
  };

  f32x4 ld[2];
  ldrnd(0, ld);
  for (int rd = 0; rd < 6; ++rd) {
    unsigned short* sb = (rd & 1) ? stg1 : stg0;
#pragma unroll
    for (int it = 0; it < 2; ++it) {   // regs -> stg (bf16 [c][i])
      int u = it * 512 + tid, cc = u >> 4, i4 = (u & 15) << 2;
      u16x4 p;
#pragma unroll
      for (int v = 0; v < 4; ++v) p[v] = f2bf(ld[it][v]);
      *(u16x4*)&sb[cc * 64 + i4] = p;
    }
    if (rd < 5) ldrnd(rd + 1, ld);     // prefetch next round's globals
    __syncthreads();
    // transpose sb -> X chunk ck, rows [rr*64, rr*64+64)
    {
      int rr = rd / 3;
      int ck = rd - rr * 3;
      int i = tid & 63;                // position within row
      int c0 = (tid >> 6) << 3;        // 0,8,...,56
      u16x8 p;
#pragma unroll
      for (int j = 0; j < 8; ++j) p[j] = sb[(c0 + j) * 64 + i];
      *(u16x8*)&X[xaddr(rr * 64 + i, ck * 64 + c0)] = p;
    }
  }
  __syncthreads();  // build complete before layer-0 reads

  // ---------------- 3 fused conv1x1+relu layers ----------------
  for (int layer = 0; layer < 3; ++layer) {
    const unsigned short* wl = wb + layer * 65536;
    const float* bias = (layer == 0) ? b1 : (layer == 1) ? b2 : b3;
    const bool al3 = (layer == 0);     // layer 0: k in [192,256) aliases chunk2 shifted

    f32x4 acc[2][8] = {};              // [mf][nf], wave tile = 32 o x 128 pos
    const int ow = wv * 32;

#pragma unroll 2
    for (int kk = 0; kk < 8; ++kk) {
      int kb = kk * 32 + g16 * 8;      // this lane-group's k-base
      bool a3 = al3 && (kk >= 6);
      int cc = a3 ? (128 + (kb & 63)) : kb;  // aliased -> chunk2 region
      bf16x8 afr[2];
#pragma unroll
      for (int mf = 0; mf < 2; ++mf)
        afr[mf] = __builtin_bit_cast(
            bf16x8, *(const u16x8*)(wl + (ow + mf * 16 + l16) * 256 + kb));
      bf16x8 bfr[4];
#pragma unroll
      for (int nf = 0; nf < 4; ++nf) { // row0 positions 0..63
        int i = nf * 16 + l16;
        int ie = a3 ? ((i - d) & 63) : i;
        bfr[nf] = __builtin_bit_cast(bf16x8, *(const u16x8*)&X[xaddr(ie, cc)]);
      }
#pragma unroll
      for (int mf = 0; mf < 2; ++mf)
#pragma unroll
        for (int nf = 0; nf < 4; ++nf)
          acc[mf][nf] = __builtin_amdgcn_mfma_f32_16x16x32_bf16(afr[mf], bfr[nf], acc[mf][nf], 0, 0, 0);
#pragma unroll
      for (int nf = 0; nf < 4; ++nf) { // row1 positions 64..127
        int i = nf * 16 + l16;
        int ie = 64 + (a3 ? ((i - d) & 63) : i);
        bfr[nf] = __builtin_bit_cast(bf16x8, *(const u16x8*)&X[xaddr(ie, cc)]);
      }
#pragma unroll
      for (int mf = 0; mf < 2; ++mf)
#pragma unroll
        for (int nf = 0; nf < 4; ++nf)
          acc[mf][4 + nf] = __builtin_amdgcn_mfma_f32_16x16x32_bf16(afr[mf], bfr[nf], acc[mf][4 + nf], 0, 0, 0);
    }
    __syncthreads();  // all waves done reading X before it is overwritten

    if (layer < 2) {
      // bias + relu -> bf16 back into X (D frag: pos = l16 col, o = g16*4+v)
#pragma unroll
      for (int mf = 0; mf < 2; ++mf) {
        int o0 = ow + mf * 16 + g16 * 4;
        f32x4 bv = *(const f32x4*)(bias + o0);
#pragma unroll
        for (int nf = 0; nf < 8; ++nf) {
          int pos = nf * 16 + l16;     // 0..127 covers both rows
          u16x4 p;
#pragma unroll
          for (int v = 0; v < 4; ++v)
            p[v] = f2bf(fmaxf(acc[mf][nf][v] + bv[v], 0.f));
          *(u16x4*)&X[xaddr(pos, o0)] = p;
        }
      }
      __syncthreads();
    } else {
      // final: bias+relu -> fp32 LDS bounce (X dead) -> f32x4 stores.
      // 4 rounds (rr,h): row rr, o in [h*128, h*128+128). Waves wv>>2==h write.
      bool first = true;
#pragma unroll
      for (int rr = 0; rr < 2; ++rr) {
#pragma unroll
        for (int h = 0; h < 2; ++h) {
          if (!first) __syncthreads();   // prev round's reads done
          first = false;
          if ((wv >> 2) == h) {
#pragma unroll
            for (int mf = 0; mf < 2; ++mf) {
              int olb = (wv & 3) * 32 + mf * 16 + g16 * 4;  // o - h*128
              f32x4 bv = *(const f32x4*)(bias + h * 128 + olb);
#pragma unroll
              for (int nq = 0; nq < 4; ++nq) {
                int pos = nq * 16 + l16;  // within-row position
#pragma unroll
                for (int v = 0; v < 4; ++v) {
                  int ol = olb + v;
                  bounce[ol * 64 + (pos ^ ((ol & 7) << 2))] =
                      fmaxf(acc[mf][rr * 4 + nq][v] + bv[v], 0.f);
                }
              }
            }
          }
          __syncthreads();
          // read back along pos, coalesced f32x4 global stores
          int bq = b0 + 16 * rr;
#pragma unroll
          for (int q = 0; q < 4; ++q) {
            int u = q * 512 + tid;
            int oh = u >> 4;             // 0..127
            int pos4 = (u & 15) << 2;
            f32x4 vv = *(const f32x4*)&bounce[oh * 64 + (pos4 ^ ((oh & 7) << 2))];
            int o = h * 128 + oh;
            *(f32x4*)&out[(((bq * 256 + o) * 63) + dd) * 64 + pos4] = vv;
          }
        }
      }
    }
  }
}

extern "C" void kernel_launch(void* const* d_in, const int* in_sizes, int n_in,
                              void* d_out, int out_size, void* d_ws, size_t ws_size,
                              hipStream_t stream) {
  const float* x  = (const float*)d_in[0];
  const float* xc = (const float*)d_in[1];
  const float* W1 = (const float*)d_in[2];
  const float* b1 = (const float*)d_in[3];
  const float* W2 = (const float*)d_in[4];
  const float* b2 = (const float*)d_in[5];
  const float* W3 = (const float*)d_in[6];
  const float* b3 = (const float*)d_in[7];
  float* out = (float*)d_out;
  unsigned short* wb = (unsigned short*)d_ws;  // 3 x 256 x 256 bf16 = 384 KB

  wconv_kernel<<<64, 256, 0, stream>>>(W1, W2, W3, wb);
  fused_kernel<<<1008, 512, 0, stream>>>(x, xc, wb, b1, b2, b3, out);
}

// Round 6
// 108.868 us; speedup vs baseline: 1.5206x; 1.5206x over previous
//
#include <hip/hip_runtime.h>
#include <stdint.h>

// pairs_of_pairs: fused [concat -> conv1x1+relu x3]
// B=32, C=64, S=64, CC=128, OC=256. 2016 rows of 64 positions.
// R5 = R4 structure with __launch_bounds__(512,2).
// Session-empirical rule: 2nd launch_bounds arg w => VGPR cap ~ 256/w.
// (512,4) forced 64 VGPR -> 217MB scratch spill (R4 regression). (512,2)
// caps at 128 >= natural ~104, so no spill; 2 blocks/CU comes from actual
// usage: 64KB LDS x2 = 128KB <= 160KB, 104 VGPR -> 4 waves/SIMD.
// Structure: 2 rows/block (b0, b0+16), grid 1008. X = 4 chunk regions
// [128pos][64ch] bf16; rolled-x chunk never stored (layer-0 k>=192 reads
// chunk2 at pos-(d) mod 64); stg double-buffer lives in chunk3 region.

typedef __attribute__((ext_vector_type(8))) __bf16 bf16x8;
typedef __attribute__((ext_vector_type(4))) float f32x4;
typedef __attribute__((ext_vector_type(4))) unsigned short u16x4;
typedef __attribute__((ext_vector_type(8))) unsigned short u16x8;

__device__ __forceinline__ unsigned short f2bf(float f) {
  unsigned int u = __builtin_bit_cast(unsigned int, f);
  u += 0x7FFFu + ((u >> 16) & 1u);
  return (unsigned short)(u >> 16);
}

// X: 4 chunk regions of [128 pos][64 ch] bf16 (8192 elems each).
// Within chunk: 16B-slot = pos*8 + ((c6/8) ^ (pos&7)) -> max 2-way (free)
// on both ds_read_b128 B-fragments and epilogue writes.
__device__ __forceinline__ int xaddr(int pos, int c) {
  int slot = (pos << 3) + ((((c & 63) >> 3) ^ pos) & 7);
  return ((c >> 6) << 13) + (slot << 3) + (c & 7);
}

__global__ void wconv_kernel(const float* __restrict__ W1, const float* __restrict__ W2,
                             const float* __restrict__ W3, unsigned short* __restrict__ wb) {
  int i = (blockIdx.x * 256 + threadIdx.x) * 4;  // grid 64 -> 65536 per layer
  const float* Ws[3] = {W1, W2, W3};
#pragma unroll
  for (int L = 0; L < 3; ++L) {
    f32x4 a = *(const f32x4*)(Ws[L] + i);
    u16x4 p;
#pragma unroll
    for (int v = 0; v < 4; ++v) p[v] = f2bf(a[v]);
    *(u16x4*)(wb + L * 65536 + i) = p;
  }
}

__global__ __launch_bounds__(512, 2)
void fused_kernel(const float* __restrict__ x, const float* __restrict__ xc,
                  const unsigned short* __restrict__ wb,
                  const float* __restrict__ b1, const float* __restrict__ b2,
                  const float* __restrict__ b3, float* __restrict__ out) {
  __shared__ __align__(16) unsigned char lraw[65536];
  unsigned short* X = (unsigned short*)lraw;                // 64KB, 4 chunks
  float* bounce = (float*)lraw;                             // 32KB epilogue reuse
  unsigned short* stg0 = (unsigned short*)(lraw + 49152);   // 8KB, in chunk3 region
  unsigned short* stg1 = (unsigned short*)(lraw + 57344);   // 8KB, in chunk3 region

  const int r = blockIdx.x;       // 0..1007
  const int b0 = r / 63;          // 0..15 ; row1 uses b0+16
  const int dd = r % 63;
  const int d = dd + 1;
  const int tid = threadIdx.x;    // 0..511
  const int lane = tid & 63;
  const int g16 = lane >> 4;
  const int l16 = lane & 15;
  const int wv = tid >> 6;        // wave 0..7

  // ---------------- build layer-0 input tiles (2 rows, 6 rounds) ----------
  // round rd: rr = rd/3 (row), ck = rd%3 (0: xc ch0-63, 1: xc ch64-127, 2: x).
  // stg double-buffered -> 1 barrier/round. No rolled chunk stored.
  auto ldrnd = [&](int rd, f32x4 ld[2]) {
    int rr = rd / 3;
    int ck = rd - rr * 3;
    int b = b0 + 16 * rr;
#pragma unroll
    for (int it = 0; it < 2; ++it) {
      int u = it * 512 + tid, cc = u >> 4, i4 = (u & 15) << 2;
      const float* src = (ck < 2)
          ? xc + (((b * 128 + ck * 64 + cc) * 63) + dd) * 64 + i4
          : x + (b * 64 + cc) * 64 + i4;
      ld[it] = *(const f32x4*)src;
    }
  };

  f32x4 ld[2];
  ldrnd(0, ld);
  for (int rd = 0; rd < 6; ++rd) {
    unsigned short* sb = (rd & 1) ? stg1 : stg0;
#pragma unroll
    for (int it = 0; it < 2; ++it) {   // regs -> stg (bf16 [c][i])
      int u = it * 512 + tid, cc = u >> 4, i4 = (u & 15) << 2;
      u16x4 p;
#pragma unroll
      for (int v = 0; v < 4; ++v) p[v] = f2bf(ld[it][v]);
      *(u16x4*)&sb[cc * 64 + i4] = p;
    }
    if (rd < 5) ldrnd(rd + 1, ld);     // prefetch next round's globals
    __syncthreads();
    // transpose sb -> X chunk ck, rows [rr*64, rr*64+64)
    {
      int rr = rd / 3;
      int ck = rd - rr * 3;
      int i = tid & 63;                // position within row
      int c0 = (tid >> 6) << 3;        // 0,8,...,56
      u16x8 p;
#pragma unroll
      for (int j = 0; j < 8; ++j) p[j] = sb[(c0 + j) * 64 + i];
      *(u16x8*)&X[xaddr(rr * 64 + i, ck * 64 + c0)] = p;
    }
  }
  __syncthreads();  // build complete before layer-0 reads

  // ---------------- 3 fused conv1x1+relu layers ----------------
  for (int layer = 0; layer < 3; ++layer) {
    const unsigned short* wl = wb + layer * 65536;
    const float* bias = (layer == 0) ? b1 : (layer == 1) ? b2 : b3;
    const bool al3 = (layer == 0);     // layer 0: k in [192,256) aliases chunk2 shifted

    f32x4 acc[2][8] = {};              // [mf][nf], wave tile = 32 o x 128 pos
    const int ow = wv * 32;

#pragma unroll 2
    for (int kk = 0; kk < 8; ++kk) {
      int kb = kk * 32 + g16 * 8;      // this lane-group's k-base
      bool a3 = al3 && (kk >= 6);
      int cc = a3 ? (128 + (kb & 63)) : kb;  // aliased -> chunk2 region
      bf16x8 afr[2];
#pragma unroll
      for (int mf = 0; mf < 2; ++mf)
        afr[mf] = __builtin_bit_cast(
            bf16x8, *(const u16x8*)(wl + (ow + mf * 16 + l16) * 256 + kb));
      bf16x8 bfr[4];
#pragma unroll
      for (int nf = 0; nf < 4; ++nf) { // row0 positions 0..63
        int i = nf * 16 + l16;
        int ie = a3 ? ((i - d) & 63) : i;
        bfr[nf] = __builtin_bit_cast(bf16x8, *(const u16x8*)&X[xaddr(ie, cc)]);
      }
#pragma unroll
      for (int mf = 0; mf < 2; ++mf)
#pragma unroll
        for (int nf = 0; nf < 4; ++nf)
          acc[mf][nf] = __builtin_amdgcn_mfma_f32_16x16x32_bf16(afr[mf], bfr[nf], acc[mf][nf], 0, 0, 0);
#pragma unroll
      for (int nf = 0; nf < 4; ++nf) { // row1 positions 64..127
        int i = nf * 16 + l16;
        int ie = 64 + (a3 ? ((i - d) & 63) : i);
        bfr[nf] = __builtin_bit_cast(bf16x8, *(const u16x8*)&X[xaddr(ie, cc)]);
      }
#pragma unroll
      for (int mf = 0; mf < 2; ++mf)
#pragma unroll
        for (int nf = 0; nf < 4; ++nf)
          acc[mf][4 + nf] = __builtin_amdgcn_mfma_f32_16x16x32_bf16(afr[mf], bfr[nf], acc[mf][4 + nf], 0, 0, 0);
    }
    __syncthreads();  // all waves done reading X before it is overwritten

    if (layer < 2) {
      // bias + relu -> bf16 back into X (D frag: pos = l16 col, o = g16*4+v)
#pragma unroll
      for (int mf = 0; mf < 2; ++mf) {
        int o0 = ow + mf * 16 + g16 * 4;
        f32x4 bv = *(const f32x4*)(bias + o0);
#pragma unroll
        for (int nf = 0; nf < 8; ++nf) {
          int pos = nf * 16 + l16;     // 0..127 covers both rows
          u16x4 p;
#pragma unroll
          for (int v = 0; v < 4; ++v)
            p[v] = f2bf(fmaxf(acc[mf][nf][v] + bv[v], 0.f));
          *(u16x4*)&X[xaddr(pos, o0)] = p;
        }
      }
      __syncthreads();
    } else {
      // final: bias+relu -> fp32 LDS bounce (X dead) -> f32x4 stores.
      // 4 rounds (rr,h): row rr, o in [h*128, h*128+128). Waves wv>>2==h write.
      bool first = true;
#pragma unroll
      for (int rr = 0; rr < 2; ++rr) {
#pragma unroll
        for (int h = 0; h < 2; ++h) {
          if (!first) __syncthreads();   // prev round's reads done
          first = false;
          if ((wv >> 2) == h) {
#pragma unroll
            for (int mf = 0; mf < 2; ++mf) {
              int olb = (wv & 3) * 32 + mf * 16 + g16 * 4;  // o - h*128
              f32x4 bv = *(const f32x4*)(bias + h * 128 + olb);
#pragma unroll
              for (int nq = 0; nq < 4; ++nq) {
                int pos = nq * 16 + l16;  // within-row position
#pragma unroll
                for (int v = 0; v < 4; ++v) {
                  int ol = olb + v;
                  bounce[ol * 64 + (pos ^ ((ol & 7) << 2))] =
                      fmaxf(acc[mf][rr * 4 + nq][v] + bv[v], 0.f);
                }
              }
            }
          }
          __syncthreads();
          // read back along pos, coalesced f32x4 global stores
          int bq = b0 + 16 * rr;
#pragma unroll
          for (int q = 0; q < 4; ++q) {
            int u = q * 512 + tid;
            int oh = u >> 4;             // 0..127
            int pos4 = (u & 15) << 2;
            f32x4 vv = *(const f32x4*)&bounce[oh * 64 + (pos4 ^ ((oh & 7) << 2))];
            int o = h * 128 + oh;
            *(f32x4*)&out[(((bq * 256 + o) * 63) + dd) * 64 + pos4] = vv;
          }
        }
      }
    }
  }
}

extern "C" void kernel_launch(void* const* d_in, const int* in_sizes, int n_in,
                              void* d_out, int out_size, void* d_ws, size_t ws_size,
                              hipStream_t stream) {
  const float* x  = (const float*)d_in[0];
  const float* xc = (const float*)d_in[1];
  const float* W1 = (const float*)d_in[2];
  const float* b1 = (const float*)d_in[3];
  const float* W2 = (const float*)d_in[4];
  const float* b2 = (const float*)d_in[5];
  const float* W3 = (const float*)d_in[6];
  const float* b3 = (const float*)d_in[7];
  float* out = (float*)d_out;
  unsigned short* wb = (unsigned short*)d_ws;  // 3 x 256 x 256 bf16 = 384 KB

  wconv_kernel<<<64, 256, 0, stream>>>(W1, W2, W3, wb);
  fused_kernel<<<1008, 512, 0, stream>>>(x, xc, wb, b1, b2, b3, out);
}